// Round 2
// baseline (496.883 us; speedup 1.0000x reference)
//
#include <hip/hip_runtime.h>

#define N_NODE   4096
#define PLANE    ((size_t)N_NODE * N_NODE)   // 16777216 floats per Chebyshev plane
#define TAU_MAX  10.0f
#define INV_SCALE 0.01f                      // 1/(T1-T0)

// Stable Softplus(beta=100): log(1+exp(100 z))/100 = (max(100z,0)+log1p(exp(-|100z|)))/100
__device__ __forceinline__ float sp100(float z) {
    float a = 100.0f * z;
    float e = __expf(-fabsf(a));
    return (fmaxf(a, 0.0f) + __logf(1.0f + e)) * 0.01f;
}

// One basis-n MLP: 1 -> 5 -> 5 -> 1, softplus100 on the two hidden layers.
// All weight indices are wave-uniform -> scalar loads + SGPR operands in v_fma.
__device__ __forceinline__ float mlp_n(float t,
                                       const float* __restrict__ W1,
                                       const float* __restrict__ b1,
                                       const float* __restrict__ W2,
                                       const float* __restrict__ b2,
                                       const float* __restrict__ W3,
                                       const float* __restrict__ b3,
                                       int n) {
    float h1[5];
#pragma unroll
    for (int w = 0; w < 5; ++w)
        h1[w] = sp100(fmaf(t, W1[n * 5 + w], b1[n * 5 + w]));

    float h2[5];
#pragma unroll
    for (int v = 0; v < 5; ++v) {
        float acc = b2[n * 5 + v];
#pragma unroll
        for (int w = 0; w < 5; ++w)
            acc = fmaf(h1[w], W2[n * 25 + w * 5 + v], acc);
        h2[v] = sp100(acc);
    }

    float o = b3[n];
#pragma unroll
    for (int w = 0; w < 5; ++w)
        o = fmaf(h2[w], W3[n * 5 + w], o);
    return o;
}

// B[4][4096][4096] -> BT[4096*4096] of float4 (the 4 Chebyshev planes interleaved).
// Reads: 4x float4 coalesced per thread; writes: 64B contiguous per thread.
__global__ __launch_bounds__(256)
void transpose_kernel(const float* __restrict__ Bm, float4* __restrict__ BT) {
    size_t t  = (size_t)blockIdx.x * blockDim.x + threadIdx.x;  // 0 .. PLANE/4-1
    size_t p0 = t * 4;
    float4 a = *(const float4*)(Bm + p0);
    float4 b = *(const float4*)(Bm + PLANE + p0);
    float4 c = *(const float4*)(Bm + 2 * PLANE + p0);
    float4 d = *(const float4*)(Bm + 3 * PLANE + p0);
    BT[p0 + 0] = make_float4(a.x, b.x, c.x, d.x);
    BT[p0 + 1] = make_float4(a.y, b.y, c.y, d.y);
    BT[p0 + 2] = make_float4(a.z, b.z, c.z, d.z);
    BT[p0 + 3] = make_float4(a.w, b.w, c.w, d.w);
}

template <bool USE_BT>
__global__ __launch_bounds__(256)
void tdb_cheb_kernel(const float2* __restrict__ x,   // [B,2] (t, node_idx)
                     const float2* __restrict__ y,   // [B,2]
                     const float*  __restrict__ Bm,  // [4, 4096, 4096] (fallback path)
                     const float4* __restrict__ BT,  // [4096*4096] interleaved (fast path)
                     const float*  __restrict__ Wx1, const float* __restrict__ Wx2,
                     const float*  __restrict__ Wx3,
                     const float*  __restrict__ Wy1, const float* __restrict__ Wy2,
                     const float*  __restrict__ Wy3,
                     const float*  __restrict__ bx1, const float* __restrict__ bx2,
                     const float*  __restrict__ bx3,
                     const float*  __restrict__ by1, const float* __restrict__ by2,
                     const float*  __restrict__ by3,
                     const float*  __restrict__ W,   // [4,4]
                     float* __restrict__ out, int batch) {
    int b = blockIdx.x * blockDim.x + threadIdx.x;
    if (b >= batch) return;

    float2 xv = x[b];
    float2 yv = y[b];
    float dt = xv.x - yv.x;

    float res = 0.0f;
    if (dt <= TAU_MAX) {   // masked lanes: out = 0, their gathers are exec-masked away
        float tx = dt * INV_SCALE;
        float ty = yv.x * INV_SCALE;   // (t_y - T0)/scale, T0 = 0

        int xi = (int)xv.y;
        int yi = (int)yv.y;
        size_t idx = (size_t)yi * N_NODE + xi;

        // Issue the gather(s) early; ~600 VALU cycles of MLP below hide the latency.
        float kl0, kl1, kl2, kl3;
        if (USE_BT) {
            float4 kl = BT[idx];                 // one 16B load, one cacheline
            kl0 = kl.x; kl1 = kl.y; kl2 = kl.z; kl3 = kl.w;
        } else {
            kl0 = Bm[idx];
            kl1 = Bm[idx + PLANE];
            kl2 = Bm[idx + 2 * PLANE];
            kl3 = Bm[idx + 3 * PLANE];
        }

        float kt[4];
#pragma unroll
        for (int n = 0; n < 4; ++n) {
            float xb = mlp_n(tx, Wx1, bx1, Wx2, bx2, Wx3, bx3, n);
            float yb = mlp_n(ty, Wy1, by1, Wy2, by2, Wy3, by3, n);
            kt[n] = xb * yb;
        }

        // out = sum_j (sum_i kt[i] * W[i][j]) * kl[j]
        float s0 = 0.f, s1 = 0.f, s2 = 0.f, s3 = 0.f;
#pragma unroll
        for (int i = 0; i < 4; ++i) {
            float k = kt[i];
            s0 = fmaf(k, W[i * 4 + 0], s0);
            s1 = fmaf(k, W[i * 4 + 1], s1);
            s2 = fmaf(k, W[i * 4 + 2], s2);
            s3 = fmaf(k, W[i * 4 + 3], s3);
        }
        res = fmaf(s0, kl0, fmaf(s1, kl1, fmaf(s2, kl2, s3 * kl3)));
    }
    out[b] = res;
}

extern "C" void kernel_launch(void* const* d_in, const int* in_sizes, int n_in,
                              void* d_out, int out_size, void* d_ws, size_t ws_size,
                              hipStream_t stream) {
    const float2* x   = (const float2*)d_in[0];
    const float2* y   = (const float2*)d_in[1];
    const float*  Bm  = (const float*)d_in[2];
    const float*  Wx1 = (const float*)d_in[3];
    const float*  Wx2 = (const float*)d_in[4];
    const float*  Wx3 = (const float*)d_in[5];
    const float*  Wy1 = (const float*)d_in[6];
    const float*  Wy2 = (const float*)d_in[7];
    const float*  Wy3 = (const float*)d_in[8];
    const float*  bx1 = (const float*)d_in[9];
    const float*  bx2 = (const float*)d_in[10];
    const float*  bx3 = (const float*)d_in[11];
    const float*  by1 = (const float*)d_in[12];
    const float*  by2 = (const float*)d_in[13];
    const float*  by3 = (const float*)d_in[14];
    const float*  W   = (const float*)d_in[15];
    float* out = (float*)d_out;

    int batch = in_sizes[0] / 2;   // x is [B,2]
    int block = 256;
    int grid  = (batch + block - 1) / block;

    const size_t bt_bytes = PLANE * 4 * sizeof(float);  // 256 MB
    if (ws_size >= bt_bytes) {
        float4* BT = (float4*)d_ws;
        int tgrid = (int)(PLANE / 4 / 256);             // 16384 blocks
        transpose_kernel<<<tgrid, 256, 0, stream>>>(Bm, BT);
        tdb_cheb_kernel<true><<<grid, block, 0, stream>>>(x, y, Bm, BT,
                                                          Wx1, Wx2, Wx3, Wy1, Wy2, Wy3,
                                                          bx1, bx2, bx3, by1, by2, by3,
                                                          W, out, batch);
    } else {
        tdb_cheb_kernel<false><<<grid, block, 0, stream>>>(x, y, Bm, (const float4*)nullptr,
                                                           Wx1, Wx2, Wx3, Wy1, Wy2, Wy3,
                                                           bx1, bx2, bx3, by1, by2, by3,
                                                           W, out, batch);
    }
}

// Round 3
// 393.960 us; speedup vs baseline: 1.2613x; 1.2613x over previous
//
#include <hip/hip_runtime.h>

#define N_NODE   4096
#define PLANE    ((size_t)N_NODE * N_NODE)   // 16777216 floats per Chebyshev plane
#define TAU_MAX  10.0f
#define INV_SCALE 0.01f                      // 1/(T1-T0)
#define TAB_N    8192                        // grid points per MLP table

// Stable Softplus(beta=100): log(1+exp(100 z))/100 = (max(100z,0)+log1p(exp(-|100z|)))/100
__device__ __forceinline__ float sp100(float z) {
    float a = 100.0f * z;
    float e = __expf(-fabsf(a));
    return (fmaxf(a, 0.0f) + __logf(1.0f + e)) * 0.01f;
}

// One basis-n MLP: 1 -> 5 -> 5 -> 1, softplus100 on the two hidden layers.
__device__ __forceinline__ float mlp_n(float t,
                                       const float* __restrict__ W1,
                                       const float* __restrict__ b1,
                                       const float* __restrict__ W2,
                                       const float* __restrict__ b2,
                                       const float* __restrict__ W3,
                                       const float* __restrict__ b3,
                                       int n) {
    float h1[5];
#pragma unroll
    for (int w = 0; w < 5; ++w)
        h1[w] = sp100(fmaf(t, W1[n * 5 + w], b1[n * 5 + w]));

    float h2[5];
#pragma unroll
    for (int v = 0; v < 5; ++v) {
        float acc = b2[n * 5 + v];
#pragma unroll
        for (int w = 0; w < 5; ++w)
            acc = fmaf(h1[w], W2[n * 25 + w * 5 + v], acc);
        h2[v] = sp100(acc);
    }

    float o = b3[n];
#pragma unroll
    for (int w = 0; w < 5; ++w)
        o = fmaf(h2[w], W3[n * 5 + w], o);
    return o;
}

// Tabulate xb_n(t) over t in [-1, 0.1] and yb_n(t) over t in [0, 1], all 4 n per row.
__global__ __launch_bounds__(256)
void build_tables(const float* __restrict__ Wx1, const float* __restrict__ Wx2,
                  const float* __restrict__ Wx3,
                  const float* __restrict__ Wy1, const float* __restrict__ Wy2,
                  const float* __restrict__ Wy3,
                  const float* __restrict__ bx1, const float* __restrict__ bx2,
                  const float* __restrict__ bx3,
                  const float* __restrict__ by1, const float* __restrict__ by2,
                  const float* __restrict__ by3,
                  float4* __restrict__ tabX, float4* __restrict__ tabY) {
    int p = blockIdx.x * blockDim.x + threadIdx.x;
    if (p >= TAB_N) return;
    float fr = (float)p / (float)(TAB_N - 1);
    float tx = fmaf(fr, 1.1f, -1.0f);   // [-1, 0.1]
    float ty = fr;                      // [0, 1]
    float4 vx, vy;
    vx.x = mlp_n(tx, Wx1, bx1, Wx2, bx2, Wx3, bx3, 0);
    vx.y = mlp_n(tx, Wx1, bx1, Wx2, bx2, Wx3, bx3, 1);
    vx.z = mlp_n(tx, Wx1, bx1, Wx2, bx2, Wx3, bx3, 2);
    vx.w = mlp_n(tx, Wx1, bx1, Wx2, bx2, Wx3, bx3, 3);
    vy.x = mlp_n(ty, Wy1, by1, Wy2, by2, Wy3, by3, 0);
    vy.y = mlp_n(ty, Wy1, by1, Wy2, by2, Wy3, by3, 1);
    vy.z = mlp_n(ty, Wy1, by1, Wy2, by2, Wy3, by3, 2);
    vy.w = mlp_n(ty, Wy1, by1, Wy2, by2, Wy3, by3, 3);
    tabX[p] = vx;
    tabY[p] = vy;
}

__device__ __forceinline__ float4 lerp4(const float4* __restrict__ tab, float u) {
    u = fminf(fmaxf(u, 0.0f), (float)(TAB_N - 1));
    int i = (int)u;
    if (i > TAB_N - 2) i = TAB_N - 2;
    float f = u - (float)i;
    float4 a = tab[i];
    float4 b = tab[i + 1];
    return make_float4(fmaf(f, b.x - a.x, a.x), fmaf(f, b.y - a.y, a.y),
                       fmaf(f, b.z - a.z, a.z), fmaf(f, b.w - a.w, a.w));
}

__global__ __launch_bounds__(256)
void tdb_cheb_kernel(const float2* __restrict__ x,   // [B,2] (t, node_idx)
                     const float2* __restrict__ y,   // [B,2]
                     const float*  __restrict__ Bm,  // [4, 4096, 4096]
                     const float4* __restrict__ tabX,
                     const float4* __restrict__ tabY,
                     const float*  __restrict__ W,   // [4,4]
                     float* __restrict__ out, int batch) {
    int b = blockIdx.x * blockDim.x + threadIdx.x;
    if (b >= batch) return;

    float2 xv = x[b];
    float2 yv = y[b];
    float dt = xv.x - yv.x;

    float res = 0.0f;
    if (dt <= TAU_MAX) {
        int xi = (int)xv.y;
        int yi = (int)yv.y;
        size_t idx = (size_t)yi * N_NODE + xi;

        // Long-latency random gathers issued first.
        float kl0 = Bm[idx];
        float kl1 = Bm[idx + PLANE];
        float kl2 = Bm[idx + 2 * PLANE];
        float kl3 = Bm[idx + 3 * PLANE];

        // MLP outputs via table interpolation (L2-resident 128 KB tables).
        float ux = (dt * INV_SCALE + 1.0f) * ((float)(TAB_N - 1) / 1.1f);
        float uy = (yv.x * INV_SCALE) * (float)(TAB_N - 1);
        float4 xb = lerp4(tabX, ux);
        float4 yb = lerp4(tabY, uy);

        float kt0 = xb.x * yb.x;
        float kt1 = xb.y * yb.y;
        float kt2 = xb.z * yb.z;
        float kt3 = xb.w * yb.w;

        // s_j = sum_i kt_i * W[i][j]; out = sum_j s_j * kl_j
        float s0 = fmaf(kt0, W[0],  fmaf(kt1, W[4],  fmaf(kt2, W[8],  kt3 * W[12])));
        float s1 = fmaf(kt0, W[1],  fmaf(kt1, W[5],  fmaf(kt2, W[9],  kt3 * W[13])));
        float s2 = fmaf(kt0, W[2],  fmaf(kt1, W[6],  fmaf(kt2, W[10], kt3 * W[14])));
        float s3 = fmaf(kt0, W[3],  fmaf(kt1, W[7],  fmaf(kt2, W[11], kt3 * W[15])));
        res = fmaf(s0, kl0, fmaf(s1, kl1, fmaf(s2, kl2, s3 * kl3)));
    }
    out[b] = res;
}

extern "C" void kernel_launch(void* const* d_in, const int* in_sizes, int n_in,
                              void* d_out, int out_size, void* d_ws, size_t ws_size,
                              hipStream_t stream) {
    const float2* x   = (const float2*)d_in[0];
    const float2* y   = (const float2*)d_in[1];
    const float*  Bm  = (const float*)d_in[2];
    const float*  Wx1 = (const float*)d_in[3];
    const float*  Wx2 = (const float*)d_in[4];
    const float*  Wx3 = (const float*)d_in[5];
    const float*  Wy1 = (const float*)d_in[6];
    const float*  Wy2 = (const float*)d_in[7];
    const float*  Wy3 = (const float*)d_in[8];
    const float*  bx1 = (const float*)d_in[9];
    const float*  bx2 = (const float*)d_in[10];
    const float*  bx3 = (const float*)d_in[11];
    const float*  by1 = (const float*)d_in[12];
    const float*  by2 = (const float*)d_in[13];
    const float*  by3 = (const float*)d_in[14];
    const float*  W   = (const float*)d_in[15];
    float* out = (float*)d_out;

    int batch = in_sizes[0] / 2;   // x is [B,2]

    float4* tabX = (float4*)d_ws;                  // 8192 * 16 B = 128 KB
    float4* tabY = tabX + TAB_N;                   // next 128 KB

    build_tables<<<(TAB_N + 255) / 256, 256, 0, stream>>>(
        Wx1, Wx2, Wx3, Wy1, Wy2, Wy3,
        bx1, bx2, bx3, by1, by2, by3, tabX, tabY);

    int block = 256;
    int grid  = (batch + block - 1) / block;
    tdb_cheb_kernel<<<grid, block, 0, stream>>>(x, y, Bm, tabX, tabY, W, out, batch);
}